// Round 4
// baseline (1557.822 us; speedup 1.0000x reference)
//
#include <hip/hip_runtime.h>
#include <hip/hip_bf16.h>
#include <stdint.h>

typedef __bf16 bf16;
typedef __bf16 bf16x8 __attribute__((ext_vector_type(8)));
typedef float floatx4 __attribute__((ext_vector_type(4)));

#define MFMA16(a, b, c) __builtin_amdgcn_mfma_f32_16x16x32_bf16((a), (b), (c), 0, 0, 0)

// load 8 consecutive elements as bf16x8 (converting if the source is f32)
static __device__ __forceinline__ bf16x8 load8(const bf16* p) {
    return *(const bf16x8*)p;
}
static __device__ __forceinline__ bf16x8 load8(const float* p) {
    const float4 a = *(const float4*)p;
    const float4 b = *(const float4*)(p + 4);
    bf16x8 r;
    r[0] = (bf16)a.x; r[1] = (bf16)a.y; r[2] = (bf16)a.z; r[3] = (bf16)a.w;
    r[4] = (bf16)b.x; r[5] = (bf16)b.y; r[6] = (bf16)b.z; r[7] = (bf16)b.w;
    return r;
}

// ---------------------------------------------------------------------------
// GEMM: C(MxN) = A(MxK) * B(KxN), B row-major KxN. A/B converted to bf16 at
// LDS staging. 128x128 tile, BK=32, 256 threads (4 waves, 2x2 of 64x64).
// M,N multiples of 128; K multiple of 32.
// ---------------------------------------------------------------------------
template <typename TA, typename TB, typename TC>
__global__ __launch_bounds__(256) void gemm_bn(const TA* __restrict__ A,
                                               const TB* __restrict__ B,
                                               TC* __restrict__ C,
                                               int M, int N, int K) {
    __shared__ __attribute__((aligned(16))) bf16 As[128 * 32];
    __shared__ __attribute__((aligned(16))) bf16 Bs[128 * 32];  // [n][k]
    const int tid = threadIdx.x;
    const int wave = tid >> 6, lane = tid & 63;
    const int quad = lane >> 4, l16 = lane & 15;
    const int m0 = blockIdx.y * 128, n0 = blockIdx.x * 128;
    const int wr = (wave >> 1) * 64, wc = (wave & 1) * 64;

    floatx4 acc[4][4] = {};

    // A staging: thread covers rows r0 and r0+64, k-chunk kc (8 elems)
    const int r0 = tid >> 2;          // 0..63
    const int kc = (tid & 3) * 8;     // 0,8,16,24
    const TA* gA0 = A + (size_t)(m0 + r0) * K + kc;
    const TA* gA1 = A + (size_t)(m0 + 64 + r0) * K + kc;

    // B staging: thread covers k-row kr, n-chunks nc8 and nc8+64
    const int kr = tid & 31;          // 0..31
    const int nc8 = (tid >> 5) * 8;   // 0,8,..,56
    const TB* gB = B + (size_t)kr * N + n0 + nc8;

    for (int k0 = 0; k0 < K; k0 += 32) {
        const bf16x8 a0 = load8(gA0 + k0);
        const bf16x8 a1 = load8(gA1 + k0);
        const TB* gBk = gB + (size_t)k0 * N;
        const bf16x8 b0 = load8(gBk);
        const bf16x8 b1 = load8(gBk + 64);
        __syncthreads();  // previous iteration's LDS reads must finish
        *(bf16x8*)&As[r0 * 32 + kc] = a0;
        *(bf16x8*)&As[(64 + r0) * 32 + kc] = a1;
#pragma unroll
        for (int j = 0; j < 8; j++) {
            Bs[(nc8 + j) * 32 + kr] = b0[j];
            Bs[(nc8 + 64 + j) * 32 + kr] = b1[j];
        }
        __syncthreads();

        bf16x8 af[4], bfr[4];
#pragma unroll
        for (int i = 0; i < 4; i++)
            af[i] = *(const bf16x8*)&As[(wr + i * 16 + l16) * 32 + quad * 8];
#pragma unroll
        for (int j = 0; j < 4; j++)
            bfr[j] = *(const bf16x8*)&Bs[(wc + j * 16 + l16) * 32 + quad * 8];
#pragma unroll
        for (int i = 0; i < 4; i++)
#pragma unroll
            for (int j = 0; j < 4; j++)
                acc[i][j] = MFMA16(af[i], bfr[j], acc[i][j]);
    }

    // epilogue: C/D layout col=lane&15, row=quad*4+reg (m89/m91 verified)
#pragma unroll
    for (int i = 0; i < 4; i++) {
#pragma unroll
        for (int j = 0; j < 4; j++) {
            const int row = m0 + wr + i * 16 + quad * 4;
            const int col = n0 + wc + j * 16 + l16;
#pragma unroll
            for (int r = 0; r < 4; r++)
                C[(size_t)(row + r) * N + col] = (TC)acc[i][j][r];
        }
    }
}

// ---------------------------------------------------------------------------
// Fused RMSNorm (over D=128) + RoPE, in place on bf16 x. Row = token*nh+head;
// s = (row/nh) % S. One wave per row; lane i holds d=i and d=i+64 (the
// rotate_half pair). w/cos/sin are float32.
// ---------------------------------------------------------------------------
__global__ __launch_bounds__(256) void rmsrope(bf16* __restrict__ x,
                                               const float* __restrict__ w,
                                               const float* __restrict__ cosb,
                                               const float* __restrict__ sinb,
                                               int nh, int S) {
    const int lane = threadIdx.x & 63;
    const int row = blockIdx.x * 4 + (threadIdx.x >> 6);
    const int s = (row / nh) % S;
    bf16* p = x + (size_t)row * 128;
    float x1 = (float)p[lane];
    float x2 = (float)p[lane + 64];
    float ssq = x1 * x1 + x2 * x2;
#pragma unroll
    for (int m = 1; m < 64; m <<= 1) ssq += __shfl_xor(ssq, m);
    const float r = rsqrtf(ssq * (1.0f / 128.0f) + 1e-6f);
    const float y1 = w[lane] * x1 * r;
    const float y2 = w[lane + 64] * x2 * r;
    const float c1 = cosb[s * 128 + lane];
    const float s1 = sinb[s * 128 + lane];
    const float c2 = cosb[s * 128 + lane + 64];
    const float s2 = sinb[s * 128 + lane + 64];
    p[lane] = (bf16)(y1 * c1 - y2 * s1);
    p[lane + 64] = (bf16)(y2 * c2 + y1 * s2);
}

// ---------------------------------------------------------------------------
// Causal GQA flash attention, output written IN PLACE over Q (all bf16).
// QO: (B*S x 4096) col = h*128+d ; K,V: (B*S x 512) col = kvh*128+d
// grid (S/64, HQ, B), 256 threads. Wave w handles q rows [q0+16w, q0+16w+16).
// ---------------------------------------------------------------------------
__global__ __launch_bounds__(256) void attn(bf16* QO,
                                            const bf16* __restrict__ Km,
                                            const bf16* __restrict__ Vm,
                                            int S) {
    __shared__ __attribute__((aligned(16))) bf16 Kl[32 * 136];   // [ki][d], pad 8
    __shared__ __attribute__((aligned(16))) bf16 Vl[128 * 40];   // [d][ki], pad 8
    __shared__ __attribute__((aligned(16))) bf16 Pl[4][16 * 40]; // per-wave P

    const int tid = threadIdx.x, wave = tid >> 6, lane = tid & 63;
    const int quad = lane >> 4, l16 = lane & 15;
    const int q0 = blockIdx.x * 64;
    const int h = blockIdx.y, b = blockIdx.z;
    const int kvh = h >> 3;  // groups = HQ/HKV = 8
    const int q_base = q0 + wave * 16;
    const float scale = 0.08838834764831845f;  // 1/sqrt(128)

    bf16x8 qf[4];
    {
        const bf16* qrow = QO + (size_t)(b * S + q_base + l16) * 4096 + h * 128 + quad * 8;
#pragma unroll
        for (int c = 0; c < 4; c++) qf[c] = *(const bf16x8*)(qrow + c * 32);
    }

    floatx4 o_acc[8] = {};
    float m_i[4], l_i[4];
#pragma unroll
    for (int r = 0; r < 4; r++) { m_i[r] = -3.0e38f; l_i[r] = 0.f; }

    const int kend = q0 + 64;
    for (int k0 = 0; k0 < kend; k0 += 32) {
#pragma unroll
        for (int it = 0; it < 2; ++it) {
            const int cc = tid + it * 256;      // 0..511 chunks of 8 elems
            const int row = cc >> 4;            // 0..31
            const int off = (cc & 15) * 8;      // 0..120
            const size_t gidx = (size_t)(b * S + k0 + row) * 512 + kvh * 128 + off;
            const bf16x8 kv = *(const bf16x8*)&Km[gidx];
            const bf16x8 vv = *(const bf16x8*)&Vm[gidx];
            *(bf16x8*)&Kl[row * 136 + off] = kv;
#pragma unroll
            for (int j = 0; j < 8; j++) Vl[(off + j) * 40 + row] = vv[j];
        }
        __syncthreads();

        if (k0 <= q_base + 15) {  // tile not fully masked for this wave
            floatx4 sc0 = {}, sc1 = {};
#pragma unroll
            for (int c = 0; c < 4; c++) {
                bf16x8 b0 = *(const bf16x8*)&Kl[l16 * 136 + c * 32 + quad * 8];
                bf16x8 b1 = *(const bf16x8*)&Kl[(l16 + 16) * 136 + c * 32 + quad * 8];
                sc0 = MFMA16(qf[c], b0, sc0);
                sc1 = MFMA16(qf[c], b1, sc1);
            }

            const bool edge = (k0 + 31 > q_base);
            float p0[4], p1[4], alpha[4];
#pragma unroll
            for (int r = 0; r < 4; r++) {
                const int qi = q_base + quad * 4 + r;
                const bool mk0 = edge && (k0 + l16 > qi);
                const bool mk1 = edge && (k0 + 16 + l16 > qi);
                const float a = mk0 ? -3.0e38f : sc0[r] * scale;
                const float z = mk1 ? -3.0e38f : sc1[r] * scale;
                float t = fmaxf(a, z);
                t = fmaxf(t, __shfl_xor(t, 1));
                t = fmaxf(t, __shfl_xor(t, 2));
                t = fmaxf(t, __shfl_xor(t, 4));
                t = fmaxf(t, __shfl_xor(t, 8));
                const float mnew = fmaxf(m_i[r], t);
                alpha[r] = __expf(m_i[r] - mnew);
                p0[r] = mk0 ? 0.f : __expf(a - mnew);
                p1[r] = mk1 ? 0.f : __expf(z - mnew);
                float srow = p0[r] + p1[r];
                srow += __shfl_xor(srow, 1);
                srow += __shfl_xor(srow, 2);
                srow += __shfl_xor(srow, 4);
                srow += __shfl_xor(srow, 8);
                l_i[r] = l_i[r] * alpha[r] + srow;
                m_i[r] = mnew;
            }

            // P: C-layout -> LDS -> A-layout (per-wave buffer)
            bf16* pw = &Pl[wave][0];
#pragma unroll
            for (int r = 0; r < 4; r++) {
                pw[(quad * 4 + r) * 40 + l16] = (bf16)p0[r];
                pw[(quad * 4 + r) * 40 + l16 + 16] = (bf16)p1[r];
            }
            const bf16x8 pa = *(const bf16x8*)&pw[l16 * 40 + quad * 8];

#pragma unroll
            for (int c = 0; c < 8; c++) {
#pragma unroll
                for (int r = 0; r < 4; r++) o_acc[c][r] *= alpha[r];
                const bf16x8 vf = *(const bf16x8*)&Vl[(c * 16 + l16) * 40 + quad * 8];
                o_acc[c] = MFMA16(pa, vf, o_acc[c]);
            }
        }
        __syncthreads();
    }

#pragma unroll
    for (int r = 0; r < 4; r++) {
        const float inv = (l_i[r] > 0.f) ? 1.0f / l_i[r] : 0.f;
        const size_t orow = (size_t)(b * S + q_base + quad * 4 + r) * 4096 + h * 128;
#pragma unroll
        for (int c = 0; c < 8; c++) {
            QO[orow + c * 16 + l16] = (bf16)(o_acc[c][r] * inv);
        }
    }
}

// ---------------------------------------------------------------------------
extern "C" void kernel_launch(void* const* d_in, const int* in_sizes, int n_in,
                              void* d_out, int out_size, void* d_ws, size_t ws_size,
                              hipStream_t stream) {
    // Reference dtypes are float32 for ALL inputs and the output.
    const float* hidden = (const float*)d_in[0];
    const float* cosb = (const float*)d_in[1];
    const float* sinb = (const float*)d_in[2];
    const float* wq = (const float*)d_in[3];
    const float* wk = (const float*)d_in[4];
    const float* wv = (const float*)d_in[5];
    const float* wo = (const float*)d_in[6];
    const float* qnw = (const float*)d_in[7];
    const float* knw = (const float*)d_in[8];
    float* out = (float*)d_out;

    constexpr int B = 2, S = 2048, HID = 2048, HQ = 32, HKV = 4, D = 128;
    constexpr int M = B * S;       // 4096
    constexpr int NQ = HQ * D;     // 4096
    constexpr int NKV = HKV * D;   // 512

    // workspace: Q (32MB) + K (4MB) + V (4MB) bf16 = 40MB total
    bf16* p = (bf16*)d_ws;
    bf16* Qb = p;  p += (size_t)M * NQ;
    bf16* Kb = p;  p += (size_t)M * NKV;
    bf16* Vb = p;  p += (size_t)M * NKV;

    // QKV projections: f32 inputs -> bf16 outputs
    gemm_bn<float, float, bf16><<<dim3(NQ / 128, M / 128), 256, 0, stream>>>(hidden, wq, Qb, M, NQ, HID);
    gemm_bn<float, float, bf16><<<dim3(NKV / 128, M / 128), 256, 0, stream>>>(hidden, wk, Kb, M, NKV, HID);
    gemm_bn<float, float, bf16><<<dim3(NKV / 128, M / 128), 256, 0, stream>>>(hidden, wv, Vb, M, NKV, HID);

    // per-head RMSNorm + RoPE (in place, bf16 data, f32 weights/tables)
    rmsrope<<<dim3(M * HQ / 4), 256, 0, stream>>>(Qb, qnw, cosb, sinb, HQ, S);
    rmsrope<<<dim3(M * HKV / 4), 256, 0, stream>>>(Kb, knw, cosb, sinb, HKV, S);

    // causal GQA attention; O overwrites Q in place
    attn<<<dim3(S / 64, HQ, B), 256, 0, stream>>>(Qb, Kb, Vb, S);

    // output projection: bf16 A, f32 B -> f32 out
    gemm_bn<bf16, float, float><<<dim3(HID / 128, M / 128), 256, 0, stream>>>(Qb, wo, out, M, HID, NQ);
}

// Round 5
// 672.195 us; speedup vs baseline: 2.3175x; 2.3175x over previous
//
#include <hip/hip_runtime.h>
#include <hip/hip_bf16.h>
#include <stdint.h>

typedef __bf16 bf16;
typedef __bf16 bf16x4 __attribute__((ext_vector_type(4)));
typedef __bf16 bf16x8 __attribute__((ext_vector_type(8)));
typedef float floatx4 __attribute__((ext_vector_type(4)));

#define MFMA16(a, b, c) __builtin_amdgcn_mfma_f32_16x16x32_bf16((a), (b), (c), 0, 0, 0)

// async global->LDS, 16B per lane; dst base wave-uniform, HW adds lane*16
static __device__ __forceinline__ void async_load16(const bf16* g, bf16* l) {
    __builtin_amdgcn_global_load_lds(
        (const __attribute__((address_space(1))) uint32_t*)(const void*)g,
        (__attribute__((address_space(3))) uint32_t*)(void*)l,
        16, 0, 0);
}

// load 8 consecutive elements as bf16x8 (converting if the source is f32)
static __device__ __forceinline__ bf16x8 load8(const bf16* p) {
    return *(const bf16x8*)p;
}
static __device__ __forceinline__ bf16x8 load8(const float* p) {
    const float4 a = *(const float4*)p;
    const float4 b = *(const float4*)(p + 4);
    bf16x8 r;
    r[0] = (bf16)a.x; r[1] = (bf16)a.y; r[2] = (bf16)a.z; r[3] = (bf16)a.w;
    r[4] = (bf16)b.x; r[5] = (bf16)b.y; r[6] = (bf16)b.z; r[7] = (bf16)b.w;
    return r;
}

// ---------------------------------------------------------------------------
// Transpose f32 (R x C) -> bf16 (C x R)
// ---------------------------------------------------------------------------
__global__ __launch_bounds__(256) void transposeF2B(const float* __restrict__ in,
                                                    bf16* __restrict__ out,
                                                    int R, int C) {
    __shared__ float t[32][33];
    const int c0 = blockIdx.x * 32, r0 = blockIdx.y * 32;
    const int tx = threadIdx.x & 31, ty = threadIdx.x >> 5;  // ty 0..7
#pragma unroll
    for (int i = 0; i < 4; i++)
        t[ty + i * 8][tx] = in[(size_t)(r0 + ty + i * 8) * C + c0 + tx];
    __syncthreads();
#pragma unroll
    for (int i = 0; i < 4; i++)
        out[(size_t)(c0 + ty + i * 8) * R + r0 + tx] = (bf16)t[tx][ty + i * 8];
}

// ---------------------------------------------------------------------------
// Fused QKV GEMM: C(M x 5120) = hidden(M x 2048, f32) * WqkvT^T.
// WqkvT is (5120 x 2048) bf16 (pre-transposed). Epilogue routes per-region:
//   n in [0,4096)      -> Q[m*4096 + n]          (bf16)
//   n in [4096,4608)   -> K[m*512 + n-4096]      (bf16)
//   n in [4608,5120)   -> Vt[(n-4608)*4096 + m]  (bf16, transposed!)
// m97 structure: 128x128 tile, BK=32, DMA staging for B, reg-convert for A.
// ---------------------------------------------------------------------------
__global__ __launch_bounds__(256) void gemm_qkv(const float* __restrict__ A,
                                                const bf16* __restrict__ BT,
                                                bf16* __restrict__ Q,
                                                bf16* __restrict__ K2,
                                                bf16* __restrict__ Vt) {
    constexpr int K = 2048;
    __shared__ __attribute__((aligned(16))) bf16 As[128 * 32];
    __shared__ __attribute__((aligned(16))) bf16 Bs[128 * 32];
    const int tid = threadIdx.x;
    const int wave = tid >> 6, lane = tid & 63;
    const int quad = lane >> 4, l16 = lane & 15;
    const int m0 = blockIdx.y * 128, n0 = blockIdx.x * 128;
    const int wr = (wave >> 1) * 64, wc = (wave & 1) * 64;

    floatx4 acc[4][4] = {};

    // A staging (f32 -> bf16 regs): rows r0, r0+64, k-chunk kc
    const int r0 = tid >> 2;
    const int kc = (tid & 3) * 8;
    const float* gA0 = A + (size_t)(m0 + r0) * K + kc;
    const float* gA1 = A + (size_t)(m0 + 64 + r0) * K + kc;
    // B staging via DMA: wave stages rows [wave*32, wave*32+32)
    const bf16* gB = BT + (size_t)(n0 + wave * 32 + (lane >> 2)) * K + (lane & 3) * 8;

    for (int k0 = 0; k0 < K; k0 += 32) {
        async_load16(gB + k0, &Bs[(wave * 32) * 32]);
        async_load16(gB + k0 + 16 * (size_t)K, &Bs[(wave * 32 + 16) * 32]);
        const bf16x8 a0 = load8(gA0 + k0);
        const bf16x8 a1 = load8(gA1 + k0);
        *(bf16x8*)&As[r0 * 32 + kc] = a0;
        *(bf16x8*)&As[(64 + r0) * 32 + kc] = a1;
        __syncthreads();

        bf16x8 af[4], bfr[4];
#pragma unroll
        for (int i = 0; i < 4; i++)
            af[i] = *(const bf16x8*)&As[(wr + i * 16 + l16) * 32 + quad * 8];
#pragma unroll
        for (int j = 0; j < 4; j++)
            bfr[j] = *(const bf16x8*)&Bs[(wc + j * 16 + l16) * 32 + quad * 8];
#pragma unroll
        for (int i = 0; i < 4; i++)
#pragma unroll
            for (int j = 0; j < 4; j++)
                acc[i][j] = MFMA16(af[i], bfr[j], acc[i][j]);
        __syncthreads();
    }

    // region is uniform per block (boundaries 4096, 4608 are multiples of 128)
    const int region = (n0 >= 4608) ? 2 : (n0 >= 4096 ? 1 : 0);
#pragma unroll
    for (int i = 0; i < 4; i++) {
#pragma unroll
        for (int j = 0; j < 4; j++) {
            const int row = m0 + wr + i * 16 + quad * 4;
            const int col = n0 + wc + j * 16 + l16;
            if (region == 0) {
#pragma unroll
                for (int r = 0; r < 4; r++)
                    Q[(size_t)(row + r) * 4096 + col] = (bf16)acc[i][j][r];
            } else if (region == 1) {
#pragma unroll
                for (int r = 0; r < 4; r++)
                    K2[(size_t)(row + r) * 512 + (col - 4096)] = (bf16)acc[i][j][r];
            } else {
                bf16x4 t;
#pragma unroll
                for (int r = 0; r < 4; r++) t[r] = (bf16)acc[i][j][r];
                *(bf16x4*)&Vt[(size_t)(col - 4608) * 4096 + row] = t;
            }
        }
    }
}

// ---------------------------------------------------------------------------
// O-projection GEMM: out(M x 2048, f32) = AO(M x 4096, bf16) * woT^T.
// woT is (2048 x 4096) bf16. Full DMA staging (m97).
// ---------------------------------------------------------------------------
__global__ __launch_bounds__(256) void gemm_o(const bf16* __restrict__ A,
                                              const bf16* __restrict__ BT,
                                              float* __restrict__ C) {
    constexpr int K = 4096, N = 2048;
    __shared__ __attribute__((aligned(16))) bf16 As[128 * 32];
    __shared__ __attribute__((aligned(16))) bf16 Bs[128 * 32];
    const int tid = threadIdx.x;
    const int wave = tid >> 6, lane = tid & 63;
    const int quad = lane >> 4, l16 = lane & 15;
    const int m0 = blockIdx.y * 128, n0 = blockIdx.x * 128;
    const int wr = (wave >> 1) * 64, wc = (wave & 1) * 64;

    floatx4 acc[4][4] = {};

    const bf16* gA = A + (size_t)(m0 + wave * 32 + (lane >> 2)) * K + (lane & 3) * 8;
    const bf16* gB = BT + (size_t)(n0 + wave * 32 + (lane >> 2)) * K + (lane & 3) * 8;

    for (int k0 = 0; k0 < K; k0 += 32) {
        async_load16(gA + k0, &As[(wave * 32) * 32]);
        async_load16(gA + k0 + 16 * (size_t)K, &As[(wave * 32 + 16) * 32]);
        async_load16(gB + k0, &Bs[(wave * 32) * 32]);
        async_load16(gB + k0 + 16 * (size_t)K, &Bs[(wave * 32 + 16) * 32]);
        __syncthreads();

        bf16x8 af[4], bfr[4];
#pragma unroll
        for (int i = 0; i < 4; i++)
            af[i] = *(const bf16x8*)&As[(wr + i * 16 + l16) * 32 + quad * 8];
#pragma unroll
        for (int j = 0; j < 4; j++)
            bfr[j] = *(const bf16x8*)&Bs[(wc + j * 16 + l16) * 32 + quad * 8];
#pragma unroll
        for (int i = 0; i < 4; i++)
#pragma unroll
            for (int j = 0; j < 4; j++)
                acc[i][j] = MFMA16(af[i], bfr[j], acc[i][j]);
        __syncthreads();
    }

#pragma unroll
    for (int i = 0; i < 4; i++) {
#pragma unroll
        for (int j = 0; j < 4; j++) {
            const int row = m0 + wr + i * 16 + quad * 4;
            const int col = n0 + wc + j * 16 + l16;
#pragma unroll
            for (int r = 0; r < 4; r++)
                C[(size_t)(row + r) * N + col] = acc[i][j][r];
        }
    }
}

// ---------------------------------------------------------------------------
// Fused RMSNorm (D=128) + RoPE, in place on bf16 x. Row = token*nh + head;
// s = (row/nh) % S. One wave per row; lane i holds d=i and d=i+64.
// ---------------------------------------------------------------------------
__global__ __launch_bounds__(256) void rmsrope(bf16* __restrict__ x,
                                               const float* __restrict__ w,
                                               const float* __restrict__ cosb,
                                               const float* __restrict__ sinb,
                                               int nh, int S) {
    const int lane = threadIdx.x & 63;
    const int row = blockIdx.x * 4 + (threadIdx.x >> 6);
    const int s = (row / nh) % S;
    bf16* p = x + (size_t)row * 128;
    float x1 = (float)p[lane];
    float x2 = (float)p[lane + 64];
    float ssq = x1 * x1 + x2 * x2;
#pragma unroll
    for (int m = 1; m < 64; m <<= 1) ssq += __shfl_xor(ssq, m);
    const float r = rsqrtf(ssq * (1.0f / 128.0f) + 1e-6f);
    const float y1 = w[lane] * x1 * r;
    const float y2 = w[lane + 64] * x2 * r;
    const float c1 = cosb[s * 128 + lane];
    const float s1 = sinb[s * 128 + lane];
    const float c2 = cosb[s * 128 + lane + 64];
    const float s2 = sinb[s * 128 + lane + 64];
    p[lane] = (bf16)(y1 * c1 - y2 * s1);
    p[lane + 64] = (bf16)(y2 * c2 + y1 * s2);
}

// ---------------------------------------------------------------------------
// Causal GQA flash attention, O written in place over Q. No online max:
// RMSNorm+RoPE bound |score*scale| <= 11.32, so exp() cannot overflow.
// QO: (B*S x 4096); K: (B*S x 512); Vt: (512 x B*S) [d-major, transposed].
// grid (S/64, HQ, B), 256 threads; wave w owns q rows [q0+16w, q0+16w+16).
// ---------------------------------------------------------------------------
__global__ __launch_bounds__(256) void attn(bf16* QO,
                                            const bf16* __restrict__ Km,
                                            const bf16* __restrict__ Vt,
                                            int S) {
    __shared__ __attribute__((aligned(16))) bf16 Kl[32 * 136];   // [ki][d]
    __shared__ __attribute__((aligned(16))) bf16 Vl[128 * 40];   // [d][ki]
    __shared__ __attribute__((aligned(16))) bf16 Pl[4][16 * 40]; // per-wave P

    const int tid = threadIdx.x, wave = tid >> 6, lane = tid & 63;
    const int quad = lane >> 4, l16 = lane & 15;
    const int q0 = blockIdx.x * 64;
    const int h = blockIdx.y, b = blockIdx.z;
    const int kvh = h >> 3;
    const int q_base = q0 + wave * 16;
    const float scale = 0.08838834764831845f;

    bf16x8 qf[4];
    {
        const bf16* qrow = QO + (size_t)(b * S + q_base + l16) * 4096 + h * 128 + quad * 8;
#pragma unroll
        for (int c = 0; c < 4; c++) qf[c] = *(const bf16x8*)(qrow + c * 32);
    }

    floatx4 o_acc[8] = {};
    float l_i[4] = {0.f, 0.f, 0.f, 0.f};

    const bf16* Kg = Km + (size_t)b * S * 512 + kvh * 128;
    const bf16* Vg = Vt + (size_t)kvh * 128 * 4096 + (size_t)b * S;

    const int kend = q0 + 64;
    for (int k0 = 0; k0 < kend; k0 += 32) {
        // K: 32 rows x 128 d, row-major b128 writes (conflict-free)
        // Vt: 128 d x 32 ki, row-major b128 writes (conflict-free)
#pragma unroll
        for (int it = 0; it < 2; ++it) {
            const int cc = tid + it * 256;       // 0..511 chunks of 8
            const int krow = cc >> 4;            // 0..31
            const int koff = (cc & 15) * 8;      // 0..120
            *(bf16x8*)&Kl[krow * 136 + koff] =
                *(const bf16x8*)&Kg[(size_t)(k0 + krow) * 512 + koff];
            const int vd = cc >> 2;              // 0..127
            const int vso = (cc & 3) * 8;        // 0..24
            *(bf16x8*)&Vl[vd * 40 + vso] =
                *(const bf16x8*)&Vg[(size_t)vd * 4096 + k0 + vso];
        }
        __syncthreads();

        if (k0 <= q_base + 15) {
            floatx4 sc0 = {}, sc1 = {};
#pragma unroll
            for (int c = 0; c < 4; c++) {
                bf16x8 b0 = *(const bf16x8*)&Kl[l16 * 136 + c * 32 + quad * 8];
                bf16x8 b1 = *(const bf16x8*)&Kl[(l16 + 16) * 136 + c * 32 + quad * 8];
                sc0 = MFMA16(qf[c], b0, sc0);
                sc1 = MFMA16(qf[c], b1, sc1);
            }

            const bool edge = (k0 + 31 > q_base);
            bf16* pw = &Pl[wave][0];
#pragma unroll
            for (int r = 0; r < 4; r++) {
                const int qi = q_base + quad * 4 + r;
                const bool mk0 = edge && (k0 + l16 > qi);
                const bool mk1 = edge && (k0 + 16 + l16 > qi);
                const float p0 = mk0 ? 0.f : __expf(sc0[r] * scale);
                const float p1 = mk1 ? 0.f : __expf(sc1[r] * scale);
                l_i[r] += p0 + p1;
                pw[(quad * 4 + r) * 40 + l16] = (bf16)p0;
                pw[(quad * 4 + r) * 40 + l16 + 16] = (bf16)p1;
            }
            const bf16x8 pa = *(const bf16x8*)&pw[l16 * 40 + quad * 8];

#pragma unroll
            for (int c = 0; c < 8; c++) {
                const bf16x8 vf = *(const bf16x8*)&Vl[(c * 16 + l16) * 40 + quad * 8];
                o_acc[c] = MFMA16(pa, vf, o_acc[c]);
            }
        }
        __syncthreads();
    }

#pragma unroll
    for (int r = 0; r < 4; r++) {
        float l = l_i[r];
        l += __shfl_xor(l, 1);
        l += __shfl_xor(l, 2);
        l += __shfl_xor(l, 4);
        l += __shfl_xor(l, 8);
        const float inv = (l > 0.f) ? 1.0f / l : 0.f;
        const size_t orow = (size_t)(b * S + q_base + quad * 4 + r) * 4096 + h * 128;
#pragma unroll
        for (int c = 0; c < 8; c++)
            QO[orow + c * 16 + l16] = (bf16)(o_acc[c][r] * inv);
    }
}

// ===========================================================================
// Fallback path (Round-4, proven; used only if ws_size < fast-path need)
// ===========================================================================
template <typename TA, typename TB, typename TC>
__global__ __launch_bounds__(256) void gemm_bn(const TA* __restrict__ A,
                                               const TB* __restrict__ B,
                                               TC* __restrict__ C,
                                               int M, int N, int K) {
    __shared__ __attribute__((aligned(16))) bf16 As[128 * 32];
    __shared__ __attribute__((aligned(16))) bf16 Bs[128 * 32];
    const int tid = threadIdx.x;
    const int wave = tid >> 6, lane = tid & 63;
    const int quad = lane >> 4, l16 = lane & 15;
    const int m0 = blockIdx.y * 128, n0 = blockIdx.x * 128;
    const int wr = (wave >> 1) * 64, wc = (wave & 1) * 64;
    floatx4 acc[4][4] = {};
    const int r0 = tid >> 2;
    const int kc = (tid & 3) * 8;
    const TA* gA0 = A + (size_t)(m0 + r0) * K + kc;
    const TA* gA1 = A + (size_t)(m0 + 64 + r0) * K + kc;
    const int kr = tid & 31;
    const int nc8 = (tid >> 5) * 8;
    const TB* gB = B + (size_t)kr * N + n0 + nc8;
    for (int k0 = 0; k0 < K; k0 += 32) {
        const bf16x8 a0 = load8(gA0 + k0);
        const bf16x8 a1 = load8(gA1 + k0);
        const TB* gBk = gB + (size_t)k0 * N;
        const bf16x8 b0 = load8(gBk);
        const bf16x8 b1 = load8(gBk + 64);
        __syncthreads();
        *(bf16x8*)&As[r0 * 32 + kc] = a0;
        *(bf16x8*)&As[(64 + r0) * 32 + kc] = a1;
#pragma unroll
        for (int j = 0; j < 8; j++) {
            Bs[(nc8 + j) * 32 + kr] = b0[j];
            Bs[(nc8 + 64 + j) * 32 + kr] = b1[j];
        }
        __syncthreads();
        bf16x8 af[4], bfr[4];
#pragma unroll
        for (int i = 0; i < 4; i++)
            af[i] = *(const bf16x8*)&As[(wr + i * 16 + l16) * 32 + quad * 8];
#pragma unroll
        for (int j = 0; j < 4; j++)
            bfr[j] = *(const bf16x8*)&Bs[(wc + j * 16 + l16) * 32 + quad * 8];
#pragma unroll
        for (int i = 0; i < 4; i++)
#pragma unroll
            for (int j = 0; j < 4; j++)
                acc[i][j] = MFMA16(af[i], bfr[j], acc[i][j]);
    }
#pragma unroll
    for (int i = 0; i < 4; i++) {
#pragma unroll
        for (int j = 0; j < 4; j++) {
            const int row = m0 + wr + i * 16 + quad * 4;
            const int col = n0 + wc + j * 16 + l16;
#pragma unroll
            for (int r = 0; r < 4; r++)
                C[(size_t)(row + r) * N + col] = (TC)acc[i][j][r];
        }
    }
}

__global__ __launch_bounds__(256) void attn_fb(bf16* QO,
                                               const bf16* __restrict__ Km,
                                               const bf16* __restrict__ Vm,
                                               int S) {
    __shared__ __attribute__((aligned(16))) bf16 Kl[32 * 136];
    __shared__ __attribute__((aligned(16))) bf16 Vl[128 * 40];
    __shared__ __attribute__((aligned(16))) bf16 Pl[4][16 * 40];
    const int tid = threadIdx.x, wave = tid >> 6, lane = tid & 63;
    const int quad = lane >> 4, l16 = lane & 15;
    const int q0 = blockIdx.x * 64;
    const int h = blockIdx.y, b = blockIdx.z;
    const int kvh = h >> 3;
    const int q_base = q0 + wave * 16;
    const float scale = 0.08838834764831845f;
    bf16x8 qf[4];
    {
        const bf16* qrow = QO + (size_t)(b * S + q_base + l16) * 4096 + h * 128 + quad * 8;
#pragma unroll
        for (int c = 0; c < 4; c++) qf[c] = *(const bf16x8*)(qrow + c * 32);
    }
    floatx4 o_acc[8] = {};
    float l_i[4] = {0.f, 0.f, 0.f, 0.f};
    const int kend = q0 + 64;
    for (int k0 = 0; k0 < kend; k0 += 32) {
#pragma unroll
        for (int it = 0; it < 2; ++it) {
            const int cc = tid + it * 256;
            const int row = cc >> 4;
            const int off = (cc & 15) * 8;
            const size_t gidx = (size_t)(b * S + k0 + row) * 512 + kvh * 128 + off;
            const bf16x8 kv = *(const bf16x8*)&Km[gidx];
            const bf16x8 vv = *(const bf16x8*)&Vm[gidx];
            *(bf16x8*)&Kl[row * 136 + off] = kv;
#pragma unroll
            for (int j = 0; j < 8; j++) Vl[(off + j) * 40 + row] = vv[j];
        }
        __syncthreads();
        if (k0 <= q_base + 15) {
            floatx4 sc0 = {}, sc1 = {};
#pragma unroll
            for (int c = 0; c < 4; c++) {
                bf16x8 b0 = *(const bf16x8*)&Kl[l16 * 136 + c * 32 + quad * 8];
                bf16x8 b1 = *(const bf16x8*)&Kl[(l16 + 16) * 136 + c * 32 + quad * 8];
                sc0 = MFMA16(qf[c], b0, sc0);
                sc1 = MFMA16(qf[c], b1, sc1);
            }
            const bool edge = (k0 + 31 > q_base);
            bf16* pw = &Pl[wave][0];
#pragma unroll
            for (int r = 0; r < 4; r++) {
                const int qi = q_base + quad * 4 + r;
                const bool mk0 = edge && (k0 + l16 > qi);
                const bool mk1 = edge && (k0 + 16 + l16 > qi);
                const float p0 = mk0 ? 0.f : __expf(sc0[r] * scale);
                const float p1 = mk1 ? 0.f : __expf(sc1[r] * scale);
                l_i[r] += p0 + p1;
                pw[(quad * 4 + r) * 40 + l16] = (bf16)p0;
                pw[(quad * 4 + r) * 40 + l16 + 16] = (bf16)p1;
            }
            const bf16x8 pa = *(const bf16x8*)&pw[l16 * 40 + quad * 8];
#pragma unroll
            for (int c = 0; c < 8; c++) {
                const bf16x8 vf = *(const bf16x8*)&Vl[(c * 16 + l16) * 40 + quad * 8];
                o_acc[c] = MFMA16(pa, vf, o_acc[c]);
            }
        }
        __syncthreads();
    }
#pragma unroll
    for (int r = 0; r < 4; r++) {
        float l = l_i[r];
        l += __shfl_xor(l, 1);
        l += __shfl_xor(l, 2);
        l += __shfl_xor(l, 4);
        l += __shfl_xor(l, 8);
        const float inv = (l > 0.f) ? 1.0f / l : 0.f;
        const size_t orow = (size_t)(b * S + q_base + quad * 4 + r) * 4096 + h * 128;
#pragma unroll
        for (int c = 0; c < 8; c++)
            QO[orow + c * 16 + l16] = (bf16)(o_acc[c][r] * inv);
    }
}

// ---------------------------------------------------------------------------
extern "C" void kernel_launch(void* const* d_in, const int* in_sizes, int n_in,
                              void* d_out, int out_size, void* d_ws, size_t ws_size,
                              hipStream_t stream) {
    const float* hidden = (const float*)d_in[0];
    const float* cosb = (const float*)d_in[1];
    const float* sinb = (const float*)d_in[2];
    const float* wq = (const float*)d_in[3];
    const float* wk = (const float*)d_in[4];
    const float* wv = (const float*)d_in[5];
    const float* wo = (const float*)d_in[6];
    const float* qnw = (const float*)d_in[7];
    const float* knw = (const float*)d_in[8];
    float* out = (float*)d_out;

    constexpr int B = 2, S = 2048, HID = 2048, HQ = 32, HKV = 4, D = 128;
    constexpr int M = B * S;       // 4096
    constexpr int NQ = HQ * D;     // 4096
    constexpr int NKV = HKV * D;   // 512
    constexpr int NQKV = NQ + 2 * NKV;  // 5120

    const size_t need = ((size_t)NQKV * HID + (size_t)HID * NQ +
                         (size_t)M * NQ + 2 * (size_t)M * NKV) * sizeof(bf16);

    if (ws_size >= need) {
        // ---------------- fast path ----------------
        bf16* p = (bf16*)d_ws;
        bf16* wqkvT = p; p += (size_t)NQKV * HID;   // (5120 x 2048)
        bf16* woT = p;   p += (size_t)HID * NQ;     // (2048 x 4096)
        bf16* Qb = p;    p += (size_t)M * NQ;
        bf16* Kb = p;    p += (size_t)M * NKV;
        bf16* Vt = p;    p += (size_t)NKV * M;      // (512 x 4096) d-major

        transposeF2B<<<dim3(NQ / 32, HID / 32), 256, 0, stream>>>(wq, wqkvT, HID, NQ);
        transposeF2B<<<dim3(NKV / 32, HID / 32), 256, 0, stream>>>(wk, wqkvT + (size_t)NQ * HID, HID, NKV);
        transposeF2B<<<dim3(NKV / 32, HID / 32), 256, 0, stream>>>(wv, wqkvT + (size_t)(NQ + NKV) * HID, HID, NKV);
        transposeF2B<<<dim3(HID / 32, NQ / 32), 256, 0, stream>>>(wo, woT, NQ, HID);

        gemm_qkv<<<dim3(NQKV / 128, M / 128), 256, 0, stream>>>(hidden, wqkvT, Qb, Kb, Vt);

        rmsrope<<<dim3(M * HQ / 4), 256, 0, stream>>>(Qb, qnw, cosb, sinb, HQ, S);
        rmsrope<<<dim3(M * HKV / 4), 256, 0, stream>>>(Kb, knw, cosb, sinb, HKV, S);

        attn<<<dim3(S / 64, HQ, B), 256, 0, stream>>>(Qb, Kb, Vt, S);

        gemm_o<<<dim3(HID / 128, M / 128), 256, 0, stream>>>(Qb, woT, out);
    } else {
        // ---------------- fallback (Round-4 structure) ----------------
        bf16* p = (bf16*)d_ws;
        bf16* Qb = p;  p += (size_t)M * NQ;
        bf16* Kb = p;  p += (size_t)M * NKV;
        bf16* Vb = p;  p += (size_t)M * NKV;

        gemm_bn<float, float, bf16><<<dim3(NQ / 128, M / 128), 256, 0, stream>>>(hidden, wq, Qb, M, NQ, HID);
        gemm_bn<float, float, bf16><<<dim3(NKV / 128, M / 128), 256, 0, stream>>>(hidden, wk, Kb, M, NKV, HID);
        gemm_bn<float, float, bf16><<<dim3(NKV / 128, M / 128), 256, 0, stream>>>(hidden, wv, Vb, M, NKV, HID);
        rmsrope<<<dim3(M * HQ / 4), 256, 0, stream>>>(Qb, qnw, cosb, sinb, HQ, S);
        rmsrope<<<dim3(M * HKV / 4), 256, 0, stream>>>(Kb, knw, cosb, sinb, HKV, S);
        attn_fb<<<dim3(S / 64, HQ, B), 256, 0, stream>>>(Qb, Kb, Vb, S);
        gemm_bn<bf16, float, float><<<dim3(HID / 128, M / 128), 256, 0, stream>>>(Qb, wo, out, M, HID, NQ);
    }
}

// Round 6
// 627.251 us; speedup vs baseline: 2.4836x; 1.0717x over previous
//
#include <hip/hip_runtime.h>
#include <hip/hip_bf16.h>
#include <stdint.h>

typedef __bf16 bf16;
typedef __bf16 bf16x4 __attribute__((ext_vector_type(4)));
typedef __bf16 bf16x8 __attribute__((ext_vector_type(8)));
typedef float floatx4 __attribute__((ext_vector_type(4)));

#define MFMA16(a, b, c) __builtin_amdgcn_mfma_f32_16x16x32_bf16((a), (b), (c), 0, 0, 0)

// async global->LDS, 16B per lane; dst base wave-uniform, HW adds lane*16
static __device__ __forceinline__ void async_load16(const bf16* g, bf16* l) {
    __builtin_amdgcn_global_load_lds(
        (const __attribute__((address_space(1))) uint32_t*)(const void*)g,
        (__attribute__((address_space(3))) uint32_t*)(void*)l,
        16, 0, 0);
}

static __device__ __forceinline__ bf16x8 load8(const bf16* p) {
    return *(const bf16x8*)p;
}
static __device__ __forceinline__ bf16x8 load8(const float* p) {
    const float4 a = *(const float4*)p;
    const float4 b = *(const float4*)(p + 4);
    bf16x8 r;
    r[0] = (bf16)a.x; r[1] = (bf16)a.y; r[2] = (bf16)a.z; r[3] = (bf16)a.w;
    r[4] = (bf16)b.x; r[5] = (bf16)b.y; r[6] = (bf16)b.z; r[7] = (bf16)b.w;
    return r;
}

// ---------------------------------------------------------------------------
// f32 -> bf16 elementwise convert (n multiple of 2048)
// ---------------------------------------------------------------------------
__global__ __launch_bounds__(256) void f2b(const float* __restrict__ in,
                                           bf16* __restrict__ out) {
    const size_t i = ((size_t)blockIdx.x * 256 + threadIdx.x) * 8;
    *(bf16x8*)&out[i] = load8(in + i);
}

// ---------------------------------------------------------------------------
// Transpose f32 (R x C) -> bf16 (C x R)
// ---------------------------------------------------------------------------
__global__ __launch_bounds__(256) void transposeF2B(const float* __restrict__ in,
                                                    bf16* __restrict__ out,
                                                    int R, int C) {
    __shared__ float t[32][33];
    const int c0 = blockIdx.x * 32, r0 = blockIdx.y * 32;
    const int tx = threadIdx.x & 31, ty = threadIdx.x >> 5;
#pragma unroll
    for (int i = 0; i < 4; i++)
        t[ty + i * 8][tx] = in[(size_t)(r0 + ty + i * 8) * C + c0 + tx];
    __syncthreads();
#pragma unroll
    for (int i = 0; i < 4; i++)
        out[(size_t)(c0 + ty + i * 8) * R + r0 + tx] = (bf16)t[tx][ty + i * 8];
}

// ---------------------------------------------------------------------------
// Fused QKV GEMM (m97, full DMA): C(M x 5120) = Ab(M x 2048, bf16) * WqkvT^T.
// Epilogue routes: n<4096 -> Q ; 4096..4608 -> K ; >=4608 -> Vt (transposed).
// ---------------------------------------------------------------------------
__global__ __launch_bounds__(256) void gemm_qkv(const bf16* __restrict__ A,
                                                const bf16* __restrict__ BT,
                                                bf16* __restrict__ Q,
                                                bf16* __restrict__ K2,
                                                bf16* __restrict__ Vt) {
    constexpr int K = 2048;
    __shared__ __attribute__((aligned(16))) bf16 As[128 * 32];
    __shared__ __attribute__((aligned(16))) bf16 Bs[128 * 32];
    const int tid = threadIdx.x;
    const int wave = tid >> 6, lane = tid & 63;
    const int quad = lane >> 4, l16 = lane & 15;
    const int m0 = blockIdx.y * 128, n0 = blockIdx.x * 128;
    const int wr = (wave >> 1) * 64, wc = (wave & 1) * 64;

    floatx4 acc[4][4] = {};

    const bf16* gA = A + (size_t)(m0 + wave * 32 + (lane >> 2)) * K + (lane & 3) * 8;
    const bf16* gB = BT + (size_t)(n0 + wave * 32 + (lane >> 2)) * K + (lane & 3) * 8;

    for (int k0 = 0; k0 < K; k0 += 32) {
        async_load16(gA + k0, &As[(wave * 32) * 32]);
        async_load16(gA + k0 + 16 * (size_t)K, &As[(wave * 32 + 16) * 32]);
        async_load16(gB + k0, &Bs[(wave * 32) * 32]);
        async_load16(gB + k0 + 16 * (size_t)K, &Bs[(wave * 32 + 16) * 32]);
        __syncthreads();

        bf16x8 af[4], bfr[4];
#pragma unroll
        for (int i = 0; i < 4; i++)
            af[i] = *(const bf16x8*)&As[(wr + i * 16 + l16) * 32 + quad * 8];
#pragma unroll
        for (int j = 0; j < 4; j++)
            bfr[j] = *(const bf16x8*)&Bs[(wc + j * 16 + l16) * 32 + quad * 8];
#pragma unroll
        for (int i = 0; i < 4; i++)
#pragma unroll
            for (int j = 0; j < 4; j++)
                acc[i][j] = MFMA16(af[i], bfr[j], acc[i][j]);
        __syncthreads();
    }

    const int region = (n0 >= 4608) ? 2 : (n0 >= 4096 ? 1 : 0);
#pragma unroll
    for (int i = 0; i < 4; i++) {
#pragma unroll
        for (int j = 0; j < 4; j++) {
            const int row = m0 + wr + i * 16 + quad * 4;
            const int col = n0 + wc + j * 16 + l16;
            if (region == 0) {
#pragma unroll
                for (int r = 0; r < 4; r++)
                    Q[(size_t)(row + r) * 4096 + col] = (bf16)acc[i][j][r];
            } else if (region == 1) {
#pragma unroll
                for (int r = 0; r < 4; r++)
                    K2[(size_t)(row + r) * 512 + (col - 4096)] = (bf16)acc[i][j][r];
            } else {
                bf16x4 t;
#pragma unroll
                for (int r = 0; r < 4; r++) t[r] = (bf16)acc[i][j][r];
                *(bf16x4*)&Vt[(size_t)(col - 4608) * 4096 + row] = t;
            }
        }
    }
}

// ---------------------------------------------------------------------------
// O-projection GEMM: out(M x 2048, f32) = AO(M x 4096, bf16) * woT^T.
// ---------------------------------------------------------------------------
__global__ __launch_bounds__(256) void gemm_o(const bf16* __restrict__ A,
                                              const bf16* __restrict__ BT,
                                              float* __restrict__ C) {
    constexpr int K = 4096, N = 2048;
    __shared__ __attribute__((aligned(16))) bf16 As[128 * 32];
    __shared__ __attribute__((aligned(16))) bf16 Bs[128 * 32];
    const int tid = threadIdx.x;
    const int wave = tid >> 6, lane = tid & 63;
    const int quad = lane >> 4, l16 = lane & 15;
    const int m0 = blockIdx.y * 128, n0 = blockIdx.x * 128;
    const int wr = (wave >> 1) * 64, wc = (wave & 1) * 64;

    floatx4 acc[4][4] = {};

    const bf16* gA = A + (size_t)(m0 + wave * 32 + (lane >> 2)) * K + (lane & 3) * 8;
    const bf16* gB = BT + (size_t)(n0 + wave * 32 + (lane >> 2)) * K + (lane & 3) * 8;

    for (int k0 = 0; k0 < K; k0 += 32) {
        async_load16(gA + k0, &As[(wave * 32) * 32]);
        async_load16(gA + k0 + 16 * (size_t)K, &As[(wave * 32 + 16) * 32]);
        async_load16(gB + k0, &Bs[(wave * 32) * 32]);
        async_load16(gB + k0 + 16 * (size_t)K, &Bs[(wave * 32 + 16) * 32]);
        __syncthreads();

        bf16x8 af[4], bfr[4];
#pragma unroll
        for (int i = 0; i < 4; i++)
            af[i] = *(const bf16x8*)&As[(wr + i * 16 + l16) * 32 + quad * 8];
#pragma unroll
        for (int j = 0; j < 4; j++)
            bfr[j] = *(const bf16x8*)&Bs[(wc + j * 16 + l16) * 32 + quad * 8];
#pragma unroll
        for (int i = 0; i < 4; i++)
#pragma unroll
            for (int j = 0; j < 4; j++)
                acc[i][j] = MFMA16(af[i], bfr[j], acc[i][j]);
        __syncthreads();
    }

#pragma unroll
    for (int i = 0; i < 4; i++) {
#pragma unroll
        for (int j = 0; j < 4; j++) {
            const int row = m0 + wr + i * 16 + quad * 4;
            const int col = n0 + wc + j * 16 + l16;
#pragma unroll
            for (int r = 0; r < 4; r++)
                C[(size_t)(row + r) * N + col] = acc[i][j][r];
        }
    }
}

// ---------------------------------------------------------------------------
// Fused RMSNorm (D=128) + RoPE, in place on bf16 x.
// ---------------------------------------------------------------------------
__global__ __launch_bounds__(256) void rmsrope(bf16* __restrict__ x,
                                               const float* __restrict__ w,
                                               const float* __restrict__ cosb,
                                               const float* __restrict__ sinb,
                                               int nh, int S) {
    const int lane = threadIdx.x & 63;
    const int row = blockIdx.x * 4 + (threadIdx.x >> 6);
    const int s = (row / nh) % S;
    bf16* p = x + (size_t)row * 128;
    float x1 = (float)p[lane];
    float x2 = (float)p[lane + 64];
    float ssq = x1 * x1 + x2 * x2;
#pragma unroll
    for (int m = 1; m < 64; m <<= 1) ssq += __shfl_xor(ssq, m);
    const float r = rsqrtf(ssq * (1.0f / 128.0f) + 1e-6f);
    const float y1 = w[lane] * x1 * r;
    const float y2 = w[lane + 64] * x2 * r;
    const float c1 = cosb[s * 128 + lane];
    const float s1 = sinb[s * 128 + lane];
    const float c2 = cosb[s * 128 + lane + 64];
    const float s2 = sinb[s * 128 + lane + 64];
    p[lane] = (bf16)(y1 * c1 - y2 * s1);
    p[lane + 64] = (bf16)(y2 * c2 + y1 * s2);
}

// ---------------------------------------------------------------------------
// Causal GQA flash attention, 128-row Q tile, O in place over Q.
// Wave w owns row groups {q0+16w, q0+64+16w} (interleaved for diagonal
// balance). K-tile 32. No online max (RMSNorm+RoPE bound |score*scale|<=11.4).
// QO: (B*S x 4096); K: (B*S x 512); Vt: (512 x B*S) d-major.
// grid (S/128, HQ, B), 256 threads.
// ---------------------------------------------------------------------------
__global__ __launch_bounds__(256) void attn(bf16* QO,
                                            const bf16* __restrict__ Km,
                                            const bf16* __restrict__ Vt,
                                            int S) {
    __shared__ __attribute__((aligned(16))) bf16 Kl[32 * 136];   // [ki][d]
    __shared__ __attribute__((aligned(16))) bf16 Vl[128 * 40];   // [d][ki]
    __shared__ __attribute__((aligned(16))) bf16 Pl[4][16 * 40]; // per-wave P

    const int tid = threadIdx.x, wave = tid >> 6, lane = tid & 63;
    const int quad = lane >> 4, l16 = lane & 15;
    const int q0 = blockIdx.x * 128;
    const int h = blockIdx.y, b = blockIdx.z;
    const int kvh = h >> 3;
    const float scale = 0.08838834764831845f;

    const int qb[2] = {q0 + wave * 16, q0 + 64 + wave * 16};

    bf16x8 qf[2][4];
#pragma unroll
    for (int g = 0; g < 2; g++) {
        const bf16* qrow = QO + (size_t)(b * S + qb[g] + l16) * 4096 + h * 128 + quad * 8;
#pragma unroll
        for (int c = 0; c < 4; c++) qf[g][c] = *(const bf16x8*)(qrow + c * 32);
    }

    floatx4 o_acc[2][8] = {};
    float l_i[2][4] = {};

    const bf16* Kg = Km + (size_t)b * S * 512 + kvh * 128;
    const bf16* Vg = Vt + (size_t)kvh * 128 * 4096 + (size_t)b * S;

    const int kend = q0 + 128;
    for (int k0 = 0; k0 < kend; k0 += 32) {
        // stage K (32x128, stride 136) and V^T (128x32, stride 40): b128 writes
#pragma unroll
        for (int it = 0; it < 2; ++it) {
            const int cc = tid + it * 256;
            const int krow = cc >> 4;            // 0..31
            const int koff = (cc & 15) * 8;      // 0..120
            *(bf16x8*)&Kl[krow * 136 + koff] =
                *(const bf16x8*)&Kg[(size_t)(k0 + krow) * 512 + koff];
            const int vd = cc >> 2;              // 0..127
            const int vso = (cc & 3) * 8;        // 0..24
            *(bf16x8*)&Vl[vd * 40 + vso] =
                *(const bf16x8*)&Vg[(size_t)vd * 4096 + k0 + vso];
        }
        __syncthreads();

#pragma unroll
        for (int g = 0; g < 2; g++) {
            if (k0 > qb[g] + 15) continue;  // fully masked for this row group

            floatx4 sc0 = {}, sc1 = {};
#pragma unroll
            for (int c = 0; c < 4; c++) {
                bf16x8 b0 = *(const bf16x8*)&Kl[l16 * 136 + c * 32 + quad * 8];
                bf16x8 b1 = *(const bf16x8*)&Kl[(l16 + 16) * 136 + c * 32 + quad * 8];
                sc0 = MFMA16(qf[g][c], b0, sc0);
                sc1 = MFMA16(qf[g][c], b1, sc1);
            }

            const bool edge = (k0 + 31 > qb[g]);
            bf16* pw = &Pl[wave][0];
#pragma unroll
            for (int r = 0; r < 4; r++) {
                const int qi = qb[g] + quad * 4 + r;
                const bool mk0 = edge && (k0 + l16 > qi);
                const bool mk1 = edge && (k0 + 16 + l16 > qi);
                const float p0 = mk0 ? 0.f : __expf(sc0[r] * scale);
                const float p1 = mk1 ? 0.f : __expf(sc1[r] * scale);
                l_i[g][r] += p0 + p1;
                pw[(quad * 4 + r) * 40 + l16] = (bf16)p0;
                pw[(quad * 4 + r) * 40 + l16 + 16] = (bf16)p1;
            }
            const bf16x8 pa = *(const bf16x8*)&pw[l16 * 40 + quad * 8];

#pragma unroll
            for (int c = 0; c < 8; c++) {
                const bf16x8 vf = *(const bf16x8*)&Vl[(c * 16 + l16) * 40 + quad * 8];
                o_acc[g][c] = MFMA16(pa, vf, o_acc[g][c]);
            }
        }
        __syncthreads();
    }

#pragma unroll
    for (int g = 0; g < 2; g++) {
#pragma unroll
        for (int r = 0; r < 4; r++) {
            float l = l_i[g][r];
            l += __shfl_xor(l, 1);
            l += __shfl_xor(l, 2);
            l += __shfl_xor(l, 4);
            l += __shfl_xor(l, 8);
            const float inv = (l > 0.f) ? 1.0f / l : 0.f;
            const size_t orow = (size_t)(b * S + qb[g] + quad * 4 + r) * 4096 + h * 128;
#pragma unroll
            for (int c = 0; c < 8; c++)
                QO[orow + c * 16 + l16] = (bf16)(o_acc[g][c][r] * inv);
        }
    }
}

// ===========================================================================
// Fallback path (Round-4, proven; used only if ws_size < fast-path need)
// ===========================================================================
template <typename TA, typename TB, typename TC>
__global__ __launch_bounds__(256) void gemm_bn(const TA* __restrict__ A,
                                               const TB* __restrict__ B,
                                               TC* __restrict__ C,
                                               int M, int N, int K) {
    __shared__ __attribute__((aligned(16))) bf16 As[128 * 32];
    __shared__ __attribute__((aligned(16))) bf16 Bs[128 * 32];
    const int tid = threadIdx.x;
    const int wave = tid >> 6, lane = tid & 63;
    const int quad = lane >> 4, l16 = lane & 15;
    const int m0 = blockIdx.y * 128, n0 = blockIdx.x * 128;
    const int wr = (wave >> 1) * 64, wc = (wave & 1) * 64;
    floatx4 acc[4][4] = {};
    const int r0 = tid >> 2;
    const int kc = (tid & 3) * 8;
    const TA* gA0 = A + (size_t)(m0 + r0) * K + kc;
    const TA* gA1 = A + (size_t)(m0 + 64 + r0) * K + kc;
    const int kr = tid & 31;
    const int nc8 = (tid >> 5) * 8;
    const TB* gB = B + (size_t)kr * N + n0 + nc8;
    for (int k0 = 0; k0 < K; k0 += 32) {
        const bf16x8 a0 = load8(gA0 + k0);
        const bf16x8 a1 = load8(gA1 + k0);
        const TB* gBk = gB + (size_t)k0 * N;
        const bf16x8 b0 = load8(gBk);
        const bf16x8 b1 = load8(gBk + 64);
        __syncthreads();
        *(bf16x8*)&As[r0 * 32 + kc] = a0;
        *(bf16x8*)&As[(64 + r0) * 32 + kc] = a1;
#pragma unroll
        for (int j = 0; j < 8; j++) {
            Bs[(nc8 + j) * 32 + kr] = b0[j];
            Bs[(nc8 + 64 + j) * 32 + kr] = b1[j];
        }
        __syncthreads();
        bf16x8 af[4], bfr[4];
#pragma unroll
        for (int i = 0; i < 4; i++)
            af[i] = *(const bf16x8*)&As[(wr + i * 16 + l16) * 32 + quad * 8];
#pragma unroll
        for (int j = 0; j < 4; j++)
            bfr[j] = *(const bf16x8*)&Bs[(wc + j * 16 + l16) * 32 + quad * 8];
#pragma unroll
        for (int i = 0; i < 4; i++)
#pragma unroll
            for (int j = 0; j < 4; j++)
                acc[i][j] = MFMA16(af[i], bfr[j], acc[i][j]);
    }
#pragma unroll
    for (int i = 0; i < 4; i++) {
#pragma unroll
        for (int j = 0; j < 4; j++) {
            const int row = m0 + wr + i * 16 + quad * 4;
            const int col = n0 + wc + j * 16 + l16;
#pragma unroll
            for (int r = 0; r < 4; r++)
                C[(size_t)(row + r) * N + col] = (TC)acc[i][j][r];
        }
    }
}

__global__ __launch_bounds__(256) void attn_fb(bf16* QO,
                                               const bf16* __restrict__ Km,
                                               const bf16* __restrict__ Vm,
                                               int S) {
    __shared__ __attribute__((aligned(16))) bf16 Kl[32 * 136];
    __shared__ __attribute__((aligned(16))) bf16 Vl[128 * 40];
    __shared__ __attribute__((aligned(16))) bf16 Pl[4][16 * 40];
    const int tid = threadIdx.x, wave = tid >> 6, lane = tid & 63;
    const int quad = lane >> 4, l16 = lane & 15;
    const int q0 = blockIdx.x * 64;
    const int h = blockIdx.y, b = blockIdx.z;
    const int kvh = h >> 3;
    const int q_base = q0 + wave * 16;
    const float scale = 0.08838834764831845f;
    bf16x8 qf[4];
    {
        const bf16* qrow = QO + (size_t)(b * S + q_base + l16) * 4096 + h * 128 + quad * 8;
#pragma unroll
        for (int c = 0; c < 4; c++) qf[c] = *(const bf16x8*)(qrow + c * 32);
    }
    floatx4 o_acc[8] = {};
    float l_i[4] = {0.f, 0.f, 0.f, 0.f};
    const int kend = q0 + 64;
    for (int k0 = 0; k0 < kend; k0 += 32) {
#pragma unroll
        for (int it = 0; it < 2; ++it) {
            const int cc = tid + it * 256;
            const int row = cc >> 4;
            const int off = (cc & 15) * 8;
            const size_t gidx = (size_t)(b * S + k0 + row) * 512 + kvh * 128 + off;
            const bf16x8 kv = *(const bf16x8*)&Km[gidx];
            const bf16x8 vv = *(const bf16x8*)&Vm[gidx];
            *(bf16x8*)&Kl[row * 136 + off] = kv;
#pragma unroll
            for (int j = 0; j < 8; j++) Vl[(off + j) * 40 + row] = vv[j];
        }
        __syncthreads();
        if (k0 <= q_base + 15) {
            floatx4 sc0 = {}, sc1 = {};
#pragma unroll
            for (int c = 0; c < 4; c++) {
                bf16x8 b0 = *(const bf16x8*)&Kl[l16 * 136 + c * 32 + quad * 8];
                bf16x8 b1 = *(const bf16x8*)&Kl[(l16 + 16) * 136 + c * 32 + quad * 8];
                sc0 = MFMA16(qf[c], b0, sc0);
                sc1 = MFMA16(qf[c], b1, sc1);
            }
            const bool edge = (k0 + 31 > q_base);
            bf16* pw = &Pl[wave][0];
#pragma unroll
            for (int r = 0; r < 4; r++) {
                const int qi = q_base + quad * 4 + r;
                const bool mk0 = edge && (k0 + l16 > qi);
                const bool mk1 = edge && (k0 + 16 + l16 > qi);
                const float p0 = mk0 ? 0.f : __expf(sc0[r] * scale);
                const float p1 = mk1 ? 0.f : __expf(sc1[r] * scale);
                l_i[r] += p0 + p1;
                pw[(quad * 4 + r) * 40 + l16] = (bf16)p0;
                pw[(quad * 4 + r) * 40 + l16 + 16] = (bf16)p1;
            }
            const bf16x8 pa = *(const bf16x8*)&pw[l16 * 40 + quad * 8];
#pragma unroll
            for (int c = 0; c < 8; c++) {
                const bf16x8 vf = *(const bf16x8*)&Vl[(c * 16 + l16) * 40 + quad * 8];
                o_acc[c] = MFMA16(pa, vf, o_acc[c]);
            }
        }
        __syncthreads();
    }
#pragma unroll
    for (int r = 0; r < 4; r++) {
        float l = l_i[r];
        l += __shfl_xor(l, 1);
        l += __shfl_xor(l, 2);
        l += __shfl_xor(l, 4);
        l += __shfl_xor(l, 8);
        const float inv = (l > 0.f) ? 1.0f / l : 0.f;
        const size_t orow = (size_t)(b * S + q_base + quad * 4 + r) * 4096 + h * 128;
#pragma unroll
        for (int c = 0; c < 8; c++)
            QO[orow + c * 16 + l16] = (bf16)(o_acc[c][r] * inv);
    }
}

// ---------------------------------------------------------------------------
extern "C" void kernel_launch(void* const* d_in, const int* in_sizes, int n_in,
                              void* d_out, int out_size, void* d_ws, size_t ws_size,
                              hipStream_t stream) {
    const float* hidden = (const float*)d_in[0];
    const float* cosb = (const float*)d_in[1];
    const float* sinb = (const float*)d_in[2];
    const float* wq = (const float*)d_in[3];
    const float* wk = (const float*)d_in[4];
    const float* wv = (const float*)d_in[5];
    const float* wo = (const float*)d_in[6];
    const float* qnw = (const float*)d_in[7];
    const float* knw = (const float*)d_in[8];
    float* out = (float*)d_out;

    constexpr int B = 2, S = 2048, HID = 2048, HQ = 32, HKV = 4, D = 128;
    constexpr int M = B * S;       // 4096
    constexpr int NQ = HQ * D;     // 4096
    constexpr int NKV = HKV * D;   // 512
    constexpr int NQKV = NQ + 2 * NKV;  // 5120

    // fast-path ws need (same as R5-proven 79.7MB): X slot is shared by
    // hiddenB (M*HID) and woT (HID*NQ) -- identical element counts.
    const size_t need = ((size_t)NQKV * HID + (size_t)HID * NQ +
                         (size_t)M * NQ + 2 * (size_t)M * NKV) * sizeof(bf16);

    if (ws_size >= need) {
        bf16* p = (bf16*)d_ws;
        bf16* wqkvT = p; p += (size_t)NQKV * HID;   // (5120 x 2048)
        bf16* X = p;     p += (size_t)HID * NQ;     // hiddenB then woT (8.39e6 el)
        bf16* Qb = p;    p += (size_t)M * NQ;
        bf16* Kb = p;    p += (size_t)M * NKV;
        bf16* Vt = p;    p += (size_t)NKV * M;      // (512 x 4096) d-major

        transposeF2B<<<dim3(NQ / 32, HID / 32), 256, 0, stream>>>(wq, wqkvT, HID, NQ);
        transposeF2B<<<dim3(NKV / 32, HID / 32), 256, 0, stream>>>(wk, wqkvT + (size_t)NQ * HID, HID, NKV);
        transposeF2B<<<dim3(NKV / 32, HID / 32), 256, 0, stream>>>(wv, wqkvT + (size_t)(NQ + NKV) * HID, HID, NKV);

        // hidden f32 -> bf16 into X
        f2b<<<dim3((M * HID) / (256 * 8)), 256, 0, stream>>>(hidden, X);

        gemm_qkv<<<dim3(NQKV / 128, M / 128), 256, 0, stream>>>(X, wqkvT, Qb, Kb, Vt);

        rmsrope<<<dim3(M * HQ / 4), 256, 0, stream>>>(Qb, qnw, cosb, sinb, HQ, S);
        rmsrope<<<dim3(M * HKV / 4), 256, 0, stream>>>(Kb, knw, cosb, sinb, HKV, S);

        attn<<<dim3(S / 128, HQ, B), 256, 0, stream>>>(Qb, Kb, Vt, S);

        // X reused: wo^T lands where hiddenB was (stream-ordered, safe)
        transposeF2B<<<dim3(HID / 32, NQ / 32), 256, 0, stream>>>(wo, X, NQ, HID);
        gemm_o<<<dim3(HID / 128, M / 128), 256, 0, stream>>>(Qb, X, out);
    } else {
        bf16* p = (bf16*)d_ws;
        bf16* Qb = p;  p += (size_t)M * NQ;
        bf16* Kb = p;  p += (size_t)M * NKV;
        bf16* Vb = p;  p += (size_t)M * NKV;

        gemm_bn<float, float, bf16><<<dim3(NQ / 128, M / 128), 256, 0, stream>>>(hidden, wq, Qb, M, NQ, HID);
        gemm_bn<float, float, bf16><<<dim3(NKV / 128, M / 128), 256, 0, stream>>>(hidden, wk, Kb, M, NKV, HID);
        gemm_bn<float, float, bf16><<<dim3(NKV / 128, M / 128), 256, 0, stream>>>(hidden, wv, Vb, M, NKV, HID);
        rmsrope<<<dim3(M * HQ / 4), 256, 0, stream>>>(Qb, qnw, cosb, sinb, HQ, S);
        rmsrope<<<dim3(M * HKV / 4), 256, 0, stream>>>(Kb, knw, cosb, sinb, HKV, S);
        attn_fb<<<dim3(S / 64, HQ, B), 256, 0, stream>>>(Qb, Kb, Vb, S);
        gemm_bn<bf16, float, float><<<dim3(HID / 128, M / 128), 256, 0, stream>>>(Qb, wo, out, M, HID, NQ);
    }
}